// Round 4
// baseline (423.395 us; speedup 1.0000x reference)
//
#include <hip/hip_runtime.h>
#include <hip/hip_bf16.h>

#define B_ROWS 65536
#define D_DIM  1024
#define NC     120   // 100 expert units + 2*10 gate logits
#define CSTR   121   // epilogue LDS stride (odd -> conflict-free row scan)

typedef __attribute__((ext_vector_type(4))) float f32x4;
typedef __attribute__((ext_vector_type(8))) short bf16x8;

__device__ __forceinline__ unsigned short f2bf(float f) {
  union { float f; unsigned u; } v; v.f = f;
  unsigned r = v.u + 0x7FFFu + ((v.u >> 16) & 1u);  // RNE
  return (unsigned short)(r >> 16);
}

__device__ __forceinline__ short f2bfs(float f) {
  __hip_bfloat16 h = __float2bfloat16(f);   // hw cvt
  return (short)__builtin_bit_cast(unsigned short, h);
}

// Pack expert_w [10][1024][10] + gate_w [2][1024][10] into bf16 Wt[c][d]
// (B^T layout, c=0..127, cols 120..127 zero). Reads coalesced; writes are
// only 256 KB scattered through L2 (cheap).
__global__ __launch_bounds__(256) void pack_w(const float* __restrict__ ew,
                                              const float* __restrict__ gw,
                                              short* __restrict__ wt) {
  int idx = blockIdx.x * 256 + threadIdx.x;   // 131072 total
  if (idx < 102400) {                          // expert_w elements
    int e = idx / 10240, r = idx % 10240, d = r / 10, u = r % 10;
    wt[(e * 10 + u) * D_DIM + d] = (short)f2bf(ew[idx]);
  } else if (idx < 122880) {                   // gate_w elements
    int j = idx - 102400;
    int t = j / 10240, r = j % 10240, d = r / 10, e2 = r % 10;
    wt[(100 + t * 10 + e2) * D_DIM + d] = (short)f2bf(gw[j]);
  } else {                                     // zero-pad cols 120..127
    int j = idx - 122880;
    wt[(120 + (j >> 10)) * D_DIM + (j & 1023)] = 0;
  }
}

// Block = 4 waves; each wave computes 32 rows x 120 cols independently.
// A: depth-2 register prefetch (3-slot ring) straight from global.
// B: depth-1 register prefetch from L2-resident wt (240 KB).
// Zero barriers in the K-loop. Reverse block order: x-restore leaves the
// tail of x L3-resident, so read tail-first.
__global__ __launch_bounds__(256, 2) void mmoe_main(
    const float* __restrict__ x, const short* __restrict__ wt,
    const float* __restrict__ eb, const float* __restrict__ gb,
    const float* __restrict__ ctr_w, const float* __restrict__ ctr_b,
    const float* __restrict__ cvr_w, const float* __restrict__ cvr_b,
    float* __restrict__ out) {
  __shared__ float C[4][32 * CSTR];   // 61952 B
  const int tid  = threadIdx.x;
  const int wave = tid >> 6, lane = tid & 63;
  const int lhi  = lane >> 4, llo = lane & 15;
  const int blk  = (int)gridDim.x - 1 - (int)blockIdx.x;
  const int m0   = blk * 128 + wave * 32;

  const float* xr0 = x + (size_t)(m0 + llo) * D_DIM + lhi * 8;   // row-tile 0
  const float* xr1 = xr0 + (size_t)16 * D_DIM;                   // row-tile 1
  const short* bb  = wt + llo * D_DIM + lhi * 8;                 // + ct*16*1024 + ks*32

  f32x4 acc[2][8];
  #pragma unroll
  for (int rt = 0; rt < 2; ++rt)
    #pragma unroll
    for (int ct = 0; ct < 8; ++ct) acc[rt][ct] = (f32x4){0.f, 0.f, 0.f, 0.f};

  float4 pa[3][2][2];   // [ring][rt][half] : A depth-2
  uint4  pb[2][8];      // [buf][ct]        : B depth-1

  // ---- prologue
  pa[0][0][0] = *(const float4*)(xr0);
  pa[0][0][1] = *(const float4*)(xr0 + 4);
  pa[0][1][0] = *(const float4*)(xr1);
  pa[0][1][1] = *(const float4*)(xr1 + 4);
  pa[1][0][0] = *(const float4*)(xr0 + 32);
  pa[1][0][1] = *(const float4*)(xr0 + 36);
  pa[1][1][0] = *(const float4*)(xr1 + 32);
  pa[1][1][1] = *(const float4*)(xr1 + 36);
  #pragma unroll
  for (int ct = 0; ct < 8; ++ct)
    pb[0][ct] = *(const uint4*)(bb + ct * 16 * D_DIM);

  #pragma unroll
  for (int ks = 0; ks < 32; ++ks) {
    const int cur3 = ks % 3;
    const int curb = ks & 1;
    if (ks + 2 < 32) {                 // A prefetch, depth 2
      const int slot = (ks + 2) % 3, kn = (ks + 2) * 32;
      pa[slot][0][0] = *(const float4*)(xr0 + kn);
      pa[slot][0][1] = *(const float4*)(xr0 + kn + 4);
      pa[slot][1][0] = *(const float4*)(xr1 + kn);
      pa[slot][1][1] = *(const float4*)(xr1 + kn + 4);
    }
    if (ks + 1 < 32) {                 // B prefetch, depth 1
      const int kn = (ks + 1) * 32;
      #pragma unroll
      for (int ct = 0; ct < 8; ++ct)
        pb[curb ^ 1][ct] = *(const uint4*)(bb + ct * 16 * D_DIM + kn);
    }
    bf16x8 af[2];
    #pragma unroll
    for (int rt = 0; rt < 2; ++rt) {
      const float4 a = pa[cur3][rt][0], b = pa[cur3][rt][1];
      af[rt][0] = f2bfs(a.x); af[rt][1] = f2bfs(a.y);
      af[rt][2] = f2bfs(a.z); af[rt][3] = f2bfs(a.w);
      af[rt][4] = f2bfs(b.x); af[rt][5] = f2bfs(b.y);
      af[rt][6] = f2bfs(b.z); af[rt][7] = f2bfs(b.w);
    }
    #pragma unroll
    for (int ct = 0; ct < 8; ++ct) {
      const bf16x8 bfr = __builtin_bit_cast(bf16x8, pb[curb][ct]);
      acc[0][ct] = __builtin_amdgcn_mfma_f32_16x16x32_bf16(af[0], bfr, acc[0][ct], 0, 0, 0);
      acc[1][ct] = __builtin_amdgcn_mfma_f32_16x16x32_bf16(af[1], bfr, acc[1][ct], 0, 0, 0);
    }
  }

  // ---- C frags -> per-wave LDS (C/D: col=lane&15, row=quad*4+reg)
  #pragma unroll
  for (int rt = 0; rt < 2; ++rt) {
    #pragma unroll
    for (int ct = 0; ct < 8; ++ct) {
      const int col = ct * 16 + llo;
      if (col < NC) {
        #pragma unroll
        for (int r = 0; r < 4; ++r)
          C[wave][(rt * 16 + lhi * 4 + r) * CSTR + col] = acc[rt][ct][r];
      }
    }
  }
  __syncthreads();

  // ---- epilogue: lane = task*32 + row
  {
    const int task = lane >> 5, row = lane & 31;
    const float* crow = &C[wave][row * CSTR];
    const float* tw = task ? cvr_w : ctr_w;
    const float tb = task ? cvr_b[0] : ctr_b[0];
    float s[10];
    #pragma unroll
    for (int e = 0; e < 10; ++e) {
      float a = 0.f;
      #pragma unroll
      for (int u = 0; u < 10; ++u) {
        float v = fmaxf(crow[e * 10 + u] + eb[e * 10 + u], 0.f);
        a = fmaf(v, tw[u], a);
      }
      s[e] = a;
    }
    float gl[10], mx = -1e30f;
    #pragma unroll
    for (int e = 0; e < 10; ++e) {
      gl[e] = crow[100 + task * 10 + e] + gb[task * 10 + e];
      mx = fmaxf(mx, gl[e]);
    }
    float den = 0.f, num = 0.f;
    #pragma unroll
    for (int e = 0; e < 10; ++e) {
      float pz = __expf(gl[e] - mx);
      den += pz; num = fmaf(pz, s[e], num);
    }
    const float z = num / den + tb;
    out[task * B_ROWS + m0 + row] = 1.f / (1.f + __expf(-z));
  }
}

extern "C" void kernel_launch(void* const* d_in, const int* in_sizes, int n_in,
                              void* d_out, int out_size, void* d_ws, size_t ws_size,
                              hipStream_t stream) {
  const float* x     = (const float*)d_in[0];
  const float* ew    = (const float*)d_in[3];
  const float* eb    = (const float*)d_in[4];
  const float* gw    = (const float*)d_in[5];
  const float* gb    = (const float*)d_in[6];
  const float* ctr_w = (const float*)d_in[7];
  const float* ctr_b = (const float*)d_in[8];
  const float* cvr_w = (const float*)d_in[9];
  const float* cvr_b = (const float*)d_in[10];
  float* out = (float*)d_out;
  short* wt  = (short*)d_ws;  // 128*1024 bf16 = 256 KB

  pack_w<<<512, 256, 0, stream>>>(ew, gw, wt);
  mmoe_main<<<B_ROWS / 128, 256, 0, stream>>>(x, wt, eb, gb, ctr_w, ctr_b,
                                              cvr_w, cvr_b, out);
}